// Round 1
// baseline (825.517 us; speedup 1.0000x reference)
//
#include <hip/hip_runtime.h>
#include <math.h>

#define ZR 128
#define NR 512

__global__ __launch_bounds__(256) void devox_kernel(
    const float* __restrict__ coords,
    const float* __restrict__ albedo,
    const float* __restrict__ normal,
    float* __restrict__ out_a,
    float* __restrict__ out_n,
    int M)
{
    int i = blockIdx.x * blockDim.x + threadIdx.x;
    if (i >= M) return;

    float cz = coords[3 * i + 0];
    float cx = coords[3 * i + 1];
    float cy = coords[3 * i + 2];

    float fz0 = floorf(cz), fx0 = floorf(cx), fy0 = floorf(cy);
    float fz = cz - fz0, fx = cx - fx0, fy = cy - fy0;

    int z0 = min(max((int)fz0, 0), ZR - 1);
    int x0 = min(max((int)fx0, 0), NR - 1);
    int y0 = min(max((int)fy0, 0), NR - 1);
    int z1 = min(z0 + 1, ZR - 1);
    int x1 = min(x0 + 1, NR - 1);
    int y1 = min(y0 + 1, NR - 1);

    float gz = 1.0f - fz, gx = 1.0f - fx, gy = 1.0f - fy;

    float w000 = gz * gx * gy, w001 = gz * gx * fy;
    float w010 = gz * fx * gy, w011 = gz * fx * fy;
    float w100 = fz * gx * gy, w101 = fz * gx * fy;
    float w110 = fz * fx * gy, w111 = fz * fx * fy;

    size_t b00 = ((size_t)z0 * NR + x0) * NR;
    size_t b01 = ((size_t)z0 * NR + x1) * NR;
    size_t b10 = ((size_t)z1 * NR + x0) * NR;
    size_t b11 = ((size_t)z1 * NR + x1) * NR;

    // albedo: 8 scalar gathers (y0/y1 adjacent -> same cache line usually)
    float a =
        albedo[b00 + y0] * w000 + albedo[b00 + y1] * w001 +
        albedo[b01 + y0] * w010 + albedo[b01 + y1] * w011 +
        albedo[b10 + y0] * w100 + albedo[b10 + y1] * w101 +
        albedo[b11 + y0] * w110 + albedo[b11 + y1] * w111;

    // normal: 8 gathers of 3 contiguous floats each
    float n0 = 0.0f, n1 = 0.0f, n2 = 0.0f;
#define ACC(base, yy, w)                                        \
    {                                                           \
        const float* p = normal + ((base) + (size_t)(yy)) * 3;  \
        n0 += p[0] * (w);                                       \
        n1 += p[1] * (w);                                       \
        n2 += p[2] * (w);                                       \
    }
    ACC(b00, y0, w000); ACC(b00, y1, w001);
    ACC(b01, y0, w010); ACC(b01, y1, w011);
    ACC(b10, y0, w100); ACC(b10, y1, w101);
    ACC(b11, y0, w110); ACC(b11, y1, w111);
#undef ACC

    // epilogue: elu(a); normalize(tanh(n) + [-1,0,0])
    a = (a > 0.0f) ? a : expm1f(a);

    n0 = tanhf(n0) - 1.0f;
    n1 = tanhf(n1);
    n2 = tanhf(n2);

    float nrm = sqrtf(n0 * n0 + n1 * n1 + n2 * n2);
    nrm = fmaxf(nrm, 1e-12f);
    float inv = 1.0f / nrm;

    out_a[i] = a;
    out_n[3 * i + 0] = n0 * inv;
    out_n[3 * i + 1] = n1 * inv;
    out_n[3 * i + 2] = n2 * inv;
}

extern "C" void kernel_launch(void* const* d_in, const int* in_sizes, int n_in,
                              void* d_out, int out_size, void* d_ws, size_t ws_size,
                              hipStream_t stream) {
    const float* coords = (const float*)d_in[0];
    const float* albedo = (const float*)d_in[1];
    const float* normal = (const float*)d_in[2];

    int M = in_sizes[0] / 3;  // coords is (M,3)
    float* out = (float*)d_out;
    float* out_a = out;          // first M floats
    float* out_n = out + M;      // next 3*M floats, row-major (M,3)

    int block = 256;
    int grid = (M + block - 1) / block;
    devox_kernel<<<grid, block, 0, stream>>>(coords, albedo, normal, out_a, out_n, M);
}